// Round 13
// baseline (230.477 us; speedup 1.0000x reference)
//
#include <hip/hip_runtime.h>

#define CIN 48
#define COUT 48
#define NPIX 16384  // 128*128
#define XFP 52      // XF pitch in shorts (104 B): bank conflicts 5.8M -> 0.88M (R11/R12)

typedef float f32x4 __attribute__((ext_vector_type(4)));
typedef short bf16x8 __attribute__((ext_vector_type(8)));

__device__ __forceinline__ unsigned short f2bf(float f) {
  unsigned u = __float_as_uint(f);
  unsigned r = (u + 0x7FFFu + ((u >> 16) & 1u)) >> 16;  // RNE
  return (unsigned short)r;
}
__device__ __forceinline__ float bf2f(unsigned short b) {
  return __uint_as_float(((unsigned)b) << 16);
}

// ws layout (floats):
//   w[20736] | ar[128] | ai[128] | pad->21248 | Up[1572864] | yf[786432] |
//   wbf64[13824] | wsplit[73728] | xfg[18874368]  => 21342464 floats
#define OFF_UP     21248
#define OFF_YF     (OFF_UP + CIN * NPIX * 2)            // 1594112
#define OFF_WBF64  (OFF_YF + CIN * NPIX)                // 2380544
#define OFF_WSPLIT (OFF_WBF64 + 13824)                  // 2394368
#define OFF_XFG    (OFF_WSPLIT + 73728)                 // 2468096
#define WS_NEEDED  ((size_t)(OFF_XFG + 48 * 48 * NPIX / 2) * 4)  // 85369856 B

// ---------------------------------------------------------------------------
// K1: Gabor weights. f32 w[oc][i][9]; bf16 outer table wbf64[(k*48+oc)*64+i]
//  (i pad 48..63 zero); if big: split inner table wsplit[i][o][64] with
//  kk=4k+{0,1,2,3} = {w0,w0,w1,w1}, kk 36..63 zero (w = w0 + w1 bf16 pair).
// ---------------------------------------------------------------------------
__global__ __launch_bounds__(256) void gabor_k(
    const float* __restrict__ freq, const float* __restrict__ theta,
    const float* __restrict__ sigma, const float* __restrict__ psi,
    const float* __restrict__ f0, const float* __restrict__ theta0,
    float* __restrict__ wout, unsigned short* __restrict__ wbf64,
    unsigned int* __restrict__ wsplitU, int big)
{
  int idx = blockIdx.x * 256 + threadIdx.x;
  if (idx < 432 * 16) {                      // zero wbf64 K-pad
    wbf64[(idx >> 4) * 64 + 48 + (idx & 15)] = 0;
  }
  if (big && idx < 2304 * 14) {              // zero wsplit kk 36..63 (14 uints/row)
    int row = idx / 14, q = idx - row * 14;
    wsplitU[row * 32 + 18 + q] = 0u;
  }
  if (idx >= COUT * CIN * 9) return;
  int k = idx % 9;
  int oi = idx / 9;
  int oc = oi / CIN, ic = oi % CIN;
  int a = k / 3, b = k % 3;
  float Yv = (a == 0) ? -1.0f : ((a == 1) ? 0.5f : 2.0f);
  float Xv = (b == 0) ? -1.0f : ((b == 1) ? 0.5f : 2.0f);
  float th = theta[oi], sg = sigma[oi], fr = freq[oi], ps = psi[oi];
  float F0 = f0[oi], th0 = theta0[oi];
  float c = cosf(th), s = sinf(th);
  float rotx =  Xv * c + Yv * s;
  float roty = -Xv * s + Yv * c;
  float r = sqrtf(rotx * rotx + roty * roty + 0.001f);
  float denom = 2.0f * logf(sg / F0);
  float t1 = (logf(r) - logf(F0)) / denom;
  float g_rad = expf(-t1 * t1);
  float dth = th - th0;
  float g_ang = expf(-dth * dth / (2.0f * sg * sg));
  float g = g_rad * g_ang * cosf(fr * r + ps) / (6.283185307179586f * sg * sg);
  wout[idx] = g;
  wbf64[(k * 48 + oc) * 64 + ic] = f2bf(g);
  if (big) {
    unsigned short w0 = f2bf(g);
    unsigned short w1 = f2bf(g - bf2f(w0));
    unsigned int u0 = (unsigned)w0 | ((unsigned)w0 << 16);
    unsigned int u1 = (unsigned)w1 | ((unsigned)w1 << 16);
    unsigned int* rowp = wsplitU + (ic * 48 + oc) * 32;  // [i][o][32 uints]
    rowp[k * 2]     = u0;
    rowp[k * 2 + 1] = u1;
  }
}

// ---------------------------------------------------------------------------
// K2: circulant band-limit vector
// ---------------------------------------------------------------------------
__global__ void circ_k(float* __restrict__ ar, float* __restrict__ ai)
{
  int d = threadIdx.x;
  float sr = 0.f, si = 0.f;
  for (int u = 34; u < 94; ++u) {
    int m = (u * d) & 127;
    float ang = (float)m * 0.049087385212340526f;
    sr += cosf(ang);
    si += sinf(ang);
  }
  ar[d] = sr * (1.0f / 128.0f);
  ai[d] = si * (1.0f / 128.0f);
}

// ---------------------------------------------------------------------------
// K3a: row band-limit. grid (8, 48).
// ---------------------------------------------------------------------------
__global__ __launch_bounds__(256) void stage1_k(
    const float* __restrict__ x, const float* __restrict__ arr,
    const float* __restrict__ aii, float2* __restrict__ Up)
{
  __shared__ float Xs[16 * 128];
  __shared__ float ars[128], ais[128];
  int yg = blockIdx.x, i = blockIdx.y;
  int t = threadIdx.x;
  const float* Xi = x + i * NPIX + yg * 16 * 128;
  for (int p = t; p < 2048; p += 256) Xs[p] = Xi[p];
  if (t < 128) { ars[t] = arr[t]; ais[t] = aii[t]; }
  __syncthreads();
  int j = t & 127;
  int ysl = t >> 7;
  float accr[8], acci[8];
#pragma unroll
  for (int yy = 0; yy < 8; ++yy) { accr[yy] = 0.f; acci[yy] = 0.f; }
  for (int xx = 0; xx < 128; ++xx) {
    float tr = ars[(j - xx) & 127];
    float ti = ais[(j - xx) & 127];
#pragma unroll
    for (int yy = 0; yy < 8; ++yy) {
      float xv = Xs[(ysl * 8 + yy) * 128 + xx];
      accr[yy] += xv * tr;
      acci[yy] += xv * ti;
    }
  }
  float2* UpI = Up + i * NPIX;
  int ybase = yg * 16 + ysl * 8;
#pragma unroll
  for (int yy = 0; yy < 8; ++yy)
    UpI[(ybase + yy) * 128 + j] = make_float2(accr[yy], acci[yy]);
}

// ---------------------------------------------------------------------------
// K3b: column band-limit. grid (8, 48). f32 output (R7: bf16 yf fails).
// ---------------------------------------------------------------------------
__global__ __launch_bounds__(256) void stage2_k(
    const float2* __restrict__ Up, const float* __restrict__ arr,
    const float* __restrict__ aii, float* __restrict__ yf)
{
  __shared__ float2 Us[128 * 16];
  __shared__ float ars[128], ais[128];
  int jg = blockIdx.x, i = blockIdx.y;
  int t = threadIdx.x;
  const float2* UpI = Up + i * NPIX;
  for (int p = t; p < 2048; p += 256) {
    int y = p >> 4, jj = p & 15;
    Us[p] = UpI[y * 128 + jg * 16 + jj];
  }
  if (t < 128) { ars[t] = arr[t]; ais[t] = aii[t]; }
  __syncthreads();
  int yp = t & 127;
  int xsl = t >> 7;
  float acc[8];
#pragma unroll
  for (int xx = 0; xx < 8; ++xx) acc[xx] = 0.f;
  for (int y = 0; y < 128; ++y) {
    float tr = ars[(yp - y) & 127];
    float ti = ais[(yp - y) & 127];
#pragma unroll
    for (int xx = 0; xx < 8; ++xx) {
      float2 u = Us[y * 16 + xsl * 8 + xx];
      acc[xx] += u.x * tr - u.y * ti;
    }
  }
  float* yfI = yf + i * NPIX;
  int xb = jg * 16 + xsl * 8;
#pragma unroll
  for (int xx = 0; xx < 8; ++xx)
    yfI[yp * 128 + xb + xx] = acc[xx];
}

// ---------------------------------------------------------------------------
// K4a (big path): inner 3x3 circular conv as MFMA GEMM per i.
//  xf_i[o][p] = sum_k w[o,i,k] * yf_i[p - shift_k]   (circular)
//  Split both sides into bf16 pairs: (w0+w1)(b0+b1) -> K = 9*4 = 36, pad 64,
//  two 16x16x32 MFMAs == f32 stencil to ~2^-16 rel, ONE bf16 round on store
//  (same rounding budget as the old in-LDS stencil; yf NOT bf16-truncated).
//  Block = (strip of 2 rows, i); M=48 o, N=256 px. Out: xfg[o][i][p] bf16.
// ---------------------------------------------------------------------------
__global__ __launch_bounds__(256, 3) void stageA_k(
    const float* __restrict__ yf, const unsigned short* __restrict__ wsplit,
    unsigned short* __restrict__ xfg)
{
  __shared__ unsigned int bpU[512];                    // [4 rows][128 cols] (b0,b1)
  __shared__ __align__(16) unsigned int BU[256 * 34];  // B [256 px][68 shorts]
  int Y0 = blockIdx.x * 2, i = blockIdx.y;
  int tid = threadIdx.x;
  const float* yfi = yf + i * NPIX;

  // A1: bf16-pair staging of source rows (Y0-2..Y0+1 mod 128)
  for (int j = tid; j < 512; j += 256) {
    int r = j >> 7, cx = j & 127;
    int gy = (Y0 - 2 + r) & 127;
    float v = yfi[gy * 128 + cx];
    unsigned short b0 = f2bf(v);
    unsigned short b1 = f2bf(v - bf2f(b0));
    bpU[j] = (unsigned)b0 | ((unsigned)b1 << 16);   // low short = b0 (kk 4k+0)
  }
  __syncthreads();

  // A2: build B rows: kk=4k+{0,1,2,3} = {b0,b1,b0,b1}; kk 36..67 zero
  {
    int px = tid;                       // ry = px>>7, x = px&127
    int ry = px >> 7, xx = px & 127;
    unsigned int* brow = BU + px * 34;
#pragma unroll
    for (int k = 0; k < 9; ++k) {
      int dy = k / 3, dx = k - dy * 3;
      int r = 2 + ry - dy;              // 0..3
      int c = (xx - dx) & 127;
      unsigned int pr = bpU[r * 128 + c];
      brow[2 * k] = pr;
      brow[2 * k + 1] = pr;
    }
#pragma unroll
    for (int q = 18; q < 34; ++q) brow[q] = 0u;
  }
  __syncthreads();

  // A3: MFMA  (A rows = o, lane tx; B cols = px, lane tx; C col=tx,row=gq*4+r)
  int wv = tid >> 6, lane = tid & 63;
  int tx = lane & 15, gq = lane >> 4;
  f32x4 acc[4][3];
#pragma unroll
  for (int nn = 0; nn < 4; ++nn)
#pragma unroll
    for (int m = 0; m < 3; ++m) acc[nn][m] = (f32x4){0.f, 0.f, 0.f, 0.f};

  const unsigned short* wsA = wsplit + i * (48 * 64);
#pragma unroll
  for (int half = 0; half < 2; ++half) {
    bf16x8 Af[3];
#pragma unroll
    for (int m = 0; m < 3; ++m)
      Af[m] = *(const bf16x8*)(wsA + (m * 16 + tx) * 64 + half * 32 + gq * 8);
#pragma unroll
    for (int nn = 0; nn < 4; ++nn) {
      int px = (wv * 4 + nn) * 16 + tx;
      bf16x8 Bf = *(const bf16x8*)((const short*)BU + px * 68 + half * 32 + gq * 8);
#pragma unroll
      for (int m = 0; m < 3; ++m)
        acc[nn][m] = __builtin_amdgcn_mfma_f32_16x16x32_bf16(Af[m], Bf, acc[nn][m], 0, 0, 0);
    }
  }

  // A4: store bf16 xf
#pragma unroll
  for (int nn = 0; nn < 4; ++nn) {
    int p = Y0 * 128 + (wv * 4 + nn) * 16 + tx;
#pragma unroll
    for (int m = 0; m < 3; ++m) {
#pragma unroll
      for (int r = 0; r < 4; ++r) {
        int o = m * 16 + gq * 4 + r;
        xfg[((size_t)(o * 48 + i) << 14) + p] = f2bf(acc[nn][m][r]);
      }
    }
  }
}

// ---------------------------------------------------------------------------
// K4b (big path): conv2 with phase-1 = pure copy/gather from xfg (no stencil).
//  Phase 2 + epilogue identical to R12.
// ---------------------------------------------------------------------------
__global__ __launch_bounds__(256, 3) void conv2g_k(
    const unsigned short* __restrict__ xfg,
    const unsigned short* __restrict__ wbf64, float* __restrict__ out)
{
  __shared__ __align__(16) short XF[324 * XFP + 16];

  int o  = blockIdx.z;
  int y0 = blockIdx.y * 16, x0 = blockIdx.x * 16;
  int tid = threadIdx.x;

  // phase 0: zero per-row pad shorts [48,52) and tail (NaN invariant)
  for (int p = tid; p < 324; p += 256)
    *(uint2*)(XF + p * XFP + 48) = make_uint2(0u, 0u);
  if (tid < 16) XF[324 * XFP + tid] = 0;

  // phase 1: gather XF[p][i] from xfg[o][i][p], zero outside [0,128)^2
  for (int task = tid; task < 864; task += 256) {
    int i = task % 48, rr = task / 48;     // adjacent lanes -> adjacent i
    int y = y0 - 1 + rr;
    short* dst = XF + rr * 18 * XFP + i;
    if (y >= 0 && y < 128) {
      const unsigned short* src = xfg + ((size_t)(o * 48 + i) << 14) + (y << 7);
      uint4 qa = *(const uint4*)(src + x0);       // shorts x0..x0+7
      uint4 qb = *(const uint4*)(src + x0 + 8);   // x0+8..x0+15
      unsigned short e0  = (x0 > 0)        ? src[x0 - 1]  : (unsigned short)0;
      unsigned short e17 = (x0 + 16 < 128) ? src[x0 + 16] : (unsigned short)0;
      unsigned int qs[8] = {qa.x, qa.y, qa.z, qa.w, qb.x, qb.y, qb.z, qb.w};
      dst[0] = (short)e0;
#pragma unroll
      for (int h = 0; h < 8; ++h) {
        dst[(2 * h + 1) * XFP] = (short)(qs[h] & 0xffffu);
        dst[(2 * h + 2) * XFP] = (short)(qs[h] >> 16);
      }
      dst[17 * XFP] = (short)e17;
    } else {
#pragma unroll
      for (int c = 0; c < 18; ++c) dst[c * XFP] = 0;
    }
  }
  __syncthreads();

  // phase 2: MFMA GEMM (verbatim R12)
  int wv = tid >> 6, lane = tid & 63;
  int tx = lane & 15, gq = lane >> 4;
  f32x4 acc[4][3];
#pragma unroll
  for (int nn = 0; nn < 4; ++nn)
#pragma unroll
    for (int m = 0; m < 3; ++m) acc[nn][m] = (f32x4){0.f, 0.f, 0.f, 0.f};

  const unsigned short* abase = wbf64 + (tx)*64;

  for (int k = 0; k < 9; ++k) {
    bf16x8 Ac0[3], Ac1[3];
#pragma unroll
    for (int m = 0; m < 3; ++m) {
      const unsigned short* ap = abase + (k * 48 + m * 16) * 64;
      Ac0[m] = *(const bf16x8*)(ap + gq * 8);
      Ac1[m] = *(const bf16x8*)(ap + 32 + gq * 8);
    }
    int dy = k / 3, dx = k - dy * 3;
#pragma unroll
    for (int nn = 0; nn < 4; ++nn) {
      int n = wv * 4 + nn;
      const short* bp = XF + ((n + dy) * 18 + tx + dx) * XFP;
      bf16x8 B0 = *(const bf16x8*)(bp + gq * 8);
      bf16x8 B1 = *(const bf16x8*)(bp + 32 + gq * 8);  // pad/next-row, A=0 there
#pragma unroll
      for (int m = 0; m < 3; ++m) {
        acc[nn][m] = __builtin_amdgcn_mfma_f32_16x16x32_bf16(Ac0[m], B0, acc[nn][m], 0, 0, 0);
        acc[nn][m] = __builtin_amdgcn_mfma_f32_16x16x32_bf16(Ac1[m], B1, acc[nn][m], 0, 0, 0);
      }
    }
  }

#pragma unroll
  for (int nn = 0; nn < 4; ++nn) {
    int y = y0 + wv * 4 + nn;
#pragma unroll
    for (int m = 0; m < 3; ++m) {
#pragma unroll
      for (int r = 0; r < 4; ++r) {
        int oc = m * 16 + gq * 4 + r;
        out[((size_t)(o * COUT + oc) << 14) + (y << 7) + x0 + tx] = acc[nn][m][r];
      }
    }
  }
}

// ---------------------------------------------------------------------------
// K4 (fallback, R12 verbatim): fused stencil + MFMA GEMM, (256,3) no-spill.
// ---------------------------------------------------------------------------
__global__ __launch_bounds__(256, 3) void conv2_k(
    const float* __restrict__ yf, const float* __restrict__ wts,
    const unsigned short* __restrict__ wbf64, float* __restrict__ out)
{
  __shared__ __align__(16) short XF[324 * XFP + 16];

  int o  = blockIdx.z;
  int y0 = blockIdx.y * 16, x0 = blockIdx.x * 16;
  int tid = threadIdx.x;

  for (int p = tid; p < 324; p += 256)
    *(uint2*)(XF + p * XFP + 48) = make_uint2(0u, 0u);
  if (tid < 16) XF[324 * XFP + tid] = 0;

  if (tid < 240) {
    int sA = tid, sB = tid + 240;
    int iA = sA / 10, rA = sA - iA * 10, spA = rA % 5, hA = rA / 5;
    int iB = sB / 10, rB = sB - iB * 10, spB = rB % 5, hB = rB / 5;
    const float* WpA = wts + (o * CIN + iA) * 9;
    const float* WpB = wts + (o * CIN + iB) * 9;
    float WA0 = WpA[0], WA1 = WpA[1], WA2 = WpA[2], WA3 = WpA[3], WA4 = WpA[4],
          WA5 = WpA[5], WA6 = WpA[6], WA7 = WpA[7], WA8 = WpA[8];
    float WB0 = WpB[0], WB1 = WpB[1], WB2 = WpB[2], WB3 = WpB[3], WB4 = WpB[4],
          WB5 = WpB[5], WB6 = WpB[6], WB7 = WpB[7], WB8 = WpB[8];
    const float* yfA = yf + iA * NPIX;
    const float* yfB = yf + iB * NPIX;
    int cbA = (x0 - 4 + 4 * spA) & 127;
    int cbB = (x0 - 4 + 4 * spB) & 127;
    int rbA = hA * 9, rbB = hB * 9;
    float RaA[8], RbA[8], RcA[8], RaB[8], RbB[8], RcB[8];

#define LOADA(dst, ry) { \
    const float* rp_ = yfA + (((ry) & 127) << 7); \
    float4 q0_ = *(const float4*)(rp_ + cbA); \
    float4 q1_ = *(const float4*)(rp_ + ((cbA + 4) & 127)); \
    dst[0]=q0_.x; dst[1]=q0_.y; dst[2]=q0_.z; dst[3]=q0_.w; \
    dst[4]=q1_.x; dst[5]=q1_.y; dst[6]=q1_.z; dst[7]=q1_.w; }
#define LOADB(dst, ry) { \
    const float* rp_ = yfB + (((ry) & 127) << 7); \
    float4 q0_ = *(const float4*)(rp_ + cbB); \
    float4 q1_ = *(const float4*)(rp_ + ((cbB + 4) & 127)); \
    dst[0]=q0_.x; dst[1]=q0_.y; dst[2]=q0_.z; dst[3]=q0_.w; \
    dst[4]=q1_.x; dst[5]=q1_.y; dst[6]=q1_.z; dst[7]=q1_.w; }
#define EMITA(rr, R2_, R1_, R0_) { \
    int y_ = y0 - 1 + (rr); \
    bool yok_ = (y_ >= 0) && (y_ < 128); \
    _Pragma("unroll") \
    for (int j = 0; j < 4; ++j) { \
      int cidx_ = 4 * spA + j; \
      if (cidx_ < 18) { \
        int xg_ = x0 - 1 + cidx_; \
        float v_ = 0.f; \
        if (yok_ && xg_ >= 0 && xg_ < 128) { \
          v_ = WA0 * R0_[j + 3] + WA1 * R0_[j + 2] + WA2 * R0_[j + 1] \
             + WA3 * R1_[j + 3] + WA4 * R1_[j + 2] + WA5 * R1_[j + 1] \
             + WA6 * R2_[j + 3] + WA7 * R2_[j + 2] + WA8 * R2_[j + 1]; \
        } \
        XF[((rr) * 18 + cidx_) * XFP + iA] = (short)f2bf(v_); \
      } } }
#define EMITB(rr, R2_, R1_, R0_) { \
    int y_ = y0 - 1 + (rr); \
    bool yok_ = (y_ >= 0) && (y_ < 128); \
    _Pragma("unroll") \
    for (int j = 0; j < 4; ++j) { \
      int cidx_ = 4 * spB + j; \
      if (cidx_ < 18) { \
        int xg_ = x0 - 1 + cidx_; \
        float v_ = 0.f; \
        if (yok_ && xg_ >= 0 && xg_ < 128) { \
          v_ = WB0 * R0_[j + 3] + WB1 * R0_[j + 2] + WB2 * R0_[j + 1] \
             + WB3 * R1_[j + 3] + WB4 * R1_[j + 2] + WB5 * R1_[j + 1] \
             + WB6 * R2_[j + 3] + WB7 * R2_[j + 2] + WB8 * R2_[j + 1]; \
        } \
        XF[((rr) * 18 + cidx_) * XFP + iB] = (short)f2bf(v_); \
      } } }

    LOADA(RaA, y0 - 3 + rbA)  LOADB(RaB, y0 - 3 + rbB)
    LOADA(RbA, y0 - 2 + rbA)  LOADB(RbB, y0 - 2 + rbB)
#pragma unroll
    for (int rr0 = 0; rr0 < 9; rr0 += 3) {
      LOADA(RcA, y0 - 1 + rbA + rr0)  LOADB(RcB, y0 - 1 + rbB + rr0)
      EMITA(rbA + rr0,     RaA, RbA, RcA)  EMITB(rbB + rr0,     RaB, RbB, RcB)
      LOADA(RaA, y0 + rbA + rr0)      LOADB(RaB, y0 + rbB + rr0)
      EMITA(rbA + rr0 + 1, RbA, RcA, RaA)  EMITB(rbB + rr0 + 1, RbB, RcB, RaB)
      LOADA(RbA, y0 + 1 + rbA + rr0)  LOADB(RbB, y0 + 1 + rbB + rr0)
      EMITA(rbA + rr0 + 2, RcA, RaA, RbA)  EMITB(rbB + rr0 + 2, RcB, RaB, RbB)
    }
#undef LOADA
#undef LOADB
#undef EMITA
#undef EMITB
  }
  __syncthreads();

  int wv = tid >> 6, lane = tid & 63;
  int tx = lane & 15, gq = lane >> 4;
  f32x4 acc[4][3];
#pragma unroll
  for (int nn = 0; nn < 4; ++nn)
#pragma unroll
    for (int m = 0; m < 3; ++m) acc[nn][m] = (f32x4){0.f, 0.f, 0.f, 0.f};

  const unsigned short* abase = wbf64 + (tx)*64;

  for (int k = 0; k < 9; ++k) {
    bf16x8 Ac0[3], Ac1[3];
#pragma unroll
    for (int m = 0; m < 3; ++m) {
      const unsigned short* ap = abase + (k * 48 + m * 16) * 64;
      Ac0[m] = *(const bf16x8*)(ap + gq * 8);
      Ac1[m] = *(const bf16x8*)(ap + 32 + gq * 8);
    }
    int dy = k / 3, dx = k - dy * 3;
#pragma unroll
    for (int nn = 0; nn < 4; ++nn) {
      int n = wv * 4 + nn;
      const short* bp = XF + ((n + dy) * 18 + tx + dx) * XFP;
      bf16x8 B0 = *(const bf16x8*)(bp + gq * 8);
      bf16x8 B1 = *(const bf16x8*)(bp + 32 + gq * 8);
#pragma unroll
      for (int m = 0; m < 3; ++m) {
        acc[nn][m] = __builtin_amdgcn_mfma_f32_16x16x32_bf16(Ac0[m], B0, acc[nn][m], 0, 0, 0);
        acc[nn][m] = __builtin_amdgcn_mfma_f32_16x16x32_bf16(Ac1[m], B1, acc[nn][m], 0, 0, 0);
      }
    }
  }

#pragma unroll
  for (int nn = 0; nn < 4; ++nn) {
    int y = y0 + wv * 4 + nn;
#pragma unroll
    for (int m = 0; m < 3; ++m) {
#pragma unroll
      for (int r = 0; r < 4; ++r) {
        int oc = m * 16 + gq * 4 + r;
        out[((size_t)(o * COUT + oc) << 14) + (y << 7) + x0 + tx] = acc[nn][m][r];
      }
    }
  }
}

// ---------------------------------------------------------------------------
extern "C" void kernel_launch(void* const* d_in, const int* in_sizes, int n_in,
                              void* d_out, int out_size, void* d_ws, size_t ws_size,
                              hipStream_t stream)
{
  const float* x      = (const float*)d_in[0];
  const float* freq   = (const float*)d_in[1];
  const float* theta  = (const float*)d_in[2];
  const float* sigma  = (const float*)d_in[3];
  const float* psi    = (const float*)d_in[4];
  const float* f0     = (const float*)d_in[5];
  const float* theta0 = (const float*)d_in[6];
  float* out = (float*)d_out;
  float* ws  = (float*)d_ws;

  float*  w      = ws;
  float*  ar     = ws + 20736;
  float*  ai     = ws + 20864;
  float2* Up     = (float2*)(ws + OFF_UP);
  float*  yf     = ws + OFF_YF;
  unsigned short* wbf64  = (unsigned short*)(ws + OFF_WBF64);
  unsigned int*   wsplit = (unsigned int*)(ws + OFF_WSPLIT);
  unsigned short* xfg    = (unsigned short*)(ws + OFF_XFG);

  int big = (ws_size >= WS_NEEDED) ? 1 : 0;

  gabor_k<<<dim3(126), dim3(256), 0, stream>>>(freq, theta, sigma, psi, f0, theta0,
                                               w, wbf64, wsplit, big);
  circ_k<<<dim3(1), dim3(128), 0, stream>>>(ar, ai);
  stage1_k<<<dim3(8, 48), dim3(256), 0, stream>>>(x, ar, ai, Up);
  stage2_k<<<dim3(8, 48), dim3(256), 0, stream>>>(Up, ar, ai, yf);
  if (big) {
    stageA_k<<<dim3(64, 48), dim3(256), 0, stream>>>(yf, (const unsigned short*)wsplit, xfg);
    conv2g_k<<<dim3(8, 8, 48), dim3(256), 0, stream>>>(xfg, wbf64, out);
  } else {
    conv2_k<<<dim3(8, 8, 48), dim3(256), 0, stream>>>(yf, w, wbf64, out);
  }
}

// Round 14
// 205.466 us; speedup vs baseline: 1.1217x; 1.1217x over previous
//
#include <hip/hip_runtime.h>

#define CIN 48
#define COUT 48
#define NPIX 16384  // 128*128
#define XFP 52      // XF pitch in shorts (104 B): bank conflicts 5.8M -> 0.88M (R11/R12)

typedef float f32x4 __attribute__((ext_vector_type(4)));
typedef short bf16x8 __attribute__((ext_vector_type(8)));

__device__ __forceinline__ unsigned short f2bf(float f) {
  unsigned u = __float_as_uint(f);
  unsigned r = (u + 0x7FFFu + ((u >> 16) & 1u)) >> 16;  // RNE
  return (unsigned short)r;
}
__device__ __forceinline__ float bf2f(unsigned short b) {
  return __uint_as_float(((unsigned)b) << 16);
}

// ws layout (floats):
//   w[20736] | ar[128] | ai[128] | pad->21248 | Up[1572864] | yf[786432] |
//   wbf64[13824] | wsplit[73728] | xfg[18874368]
#define OFF_UP     21248
#define OFF_YF     (OFF_UP + CIN * NPIX * 2)
#define OFF_WBF64  (OFF_YF + CIN * NPIX)
#define OFF_WSPLIT (OFF_WBF64 + 13824)
#define OFF_XFG    (OFF_WSPLIT + 73728)
#define WS_NEEDED  ((size_t)(OFF_XFG + 48 * 48 * NPIX / 2) * 4)

// ---------------------------------------------------------------------------
// K1: Gabor weights (unchanged from R13, passing)
// ---------------------------------------------------------------------------
__global__ __launch_bounds__(256) void gabor_k(
    const float* __restrict__ freq, const float* __restrict__ theta,
    const float* __restrict__ sigma, const float* __restrict__ psi,
    const float* __restrict__ f0, const float* __restrict__ theta0,
    float* __restrict__ wout, unsigned short* __restrict__ wbf64,
    unsigned int* __restrict__ wsplitU, int big)
{
  int idx = blockIdx.x * 256 + threadIdx.x;
  if (idx < 432 * 16) {
    wbf64[(idx >> 4) * 64 + 48 + (idx & 15)] = 0;
  }
  if (big && idx < 2304 * 14) {
    int row = idx / 14, q = idx - row * 14;
    wsplitU[row * 32 + 18 + q] = 0u;
  }
  if (idx >= COUT * CIN * 9) return;
  int k = idx % 9;
  int oi = idx / 9;
  int oc = oi / CIN, ic = oi % CIN;
  int a = k / 3, b = k % 3;
  float Yv = (a == 0) ? -1.0f : ((a == 1) ? 0.5f : 2.0f);
  float Xv = (b == 0) ? -1.0f : ((b == 1) ? 0.5f : 2.0f);
  float th = theta[oi], sg = sigma[oi], fr = freq[oi], ps = psi[oi];
  float F0 = f0[oi], th0 = theta0[oi];
  float c = cosf(th), s = sinf(th);
  float rotx =  Xv * c + Yv * s;
  float roty = -Xv * s + Yv * c;
  float r = sqrtf(rotx * rotx + roty * roty + 0.001f);
  float denom = 2.0f * logf(sg / F0);
  float t1 = (logf(r) - logf(F0)) / denom;
  float g_rad = expf(-t1 * t1);
  float dth = th - th0;
  float g_ang = expf(-dth * dth / (2.0f * sg * sg));
  float g = g_rad * g_ang * cosf(fr * r + ps) / (6.283185307179586f * sg * sg);
  wout[idx] = g;
  wbf64[(k * 48 + oc) * 64 + ic] = f2bf(g);
  if (big) {
    unsigned short w0 = f2bf(g);
    unsigned short w1 = f2bf(g - bf2f(w0));
    unsigned int u0 = (unsigned)w0 | ((unsigned)w0 << 16);
    unsigned int u1 = (unsigned)w1 | ((unsigned)w1 << 16);
    unsigned int* rowp = wsplitU + (ic * 48 + oc) * 32;
    rowp[k * 2]     = u0;
    rowp[k * 2 + 1] = u1;
  }
}

// ---------------------------------------------------------------------------
// K2: circulant band-limit vector
// ---------------------------------------------------------------------------
__global__ void circ_k(float* __restrict__ ar, float* __restrict__ ai)
{
  int d = threadIdx.x;
  float sr = 0.f, si = 0.f;
  for (int u = 34; u < 94; ++u) {
    int m = (u * d) & 127;
    float ang = (float)m * 0.049087385212340526f;
    sr += cosf(ang);
    si += sinf(ang);
  }
  ar[d] = sr * (1.0f / 128.0f);
  ai[d] = si * (1.0f / 128.0f);
}

// ---------------------------------------------------------------------------
// K3a: row band-limit. grid (8, 48).
// ---------------------------------------------------------------------------
__global__ __launch_bounds__(256) void stage1_k(
    const float* __restrict__ x, const float* __restrict__ arr,
    const float* __restrict__ aii, float2* __restrict__ Up)
{
  __shared__ float Xs[16 * 128];
  __shared__ float ars[128], ais[128];
  int yg = blockIdx.x, i = blockIdx.y;
  int t = threadIdx.x;
  const float* Xi = x + i * NPIX + yg * 16 * 128;
  for (int p = t; p < 2048; p += 256) Xs[p] = Xi[p];
  if (t < 128) { ars[t] = arr[t]; ais[t] = aii[t]; }
  __syncthreads();
  int j = t & 127;
  int ysl = t >> 7;
  float accr[8], acci[8];
#pragma unroll
  for (int yy = 0; yy < 8; ++yy) { accr[yy] = 0.f; acci[yy] = 0.f; }
  for (int xx = 0; xx < 128; ++xx) {
    float tr = ars[(j - xx) & 127];
    float ti = ais[(j - xx) & 127];
#pragma unroll
    for (int yy = 0; yy < 8; ++yy) {
      float xv = Xs[(ysl * 8 + yy) * 128 + xx];
      accr[yy] += xv * tr;
      acci[yy] += xv * ti;
    }
  }
  float2* UpI = Up + i * NPIX;
  int ybase = yg * 16 + ysl * 8;
#pragma unroll
  for (int yy = 0; yy < 8; ++yy)
    UpI[(ybase + yy) * 128 + j] = make_float2(accr[yy], acci[yy]);
}

// ---------------------------------------------------------------------------
// K3b: column band-limit. grid (8, 48). f32 output (R7: bf16 yf fails).
// ---------------------------------------------------------------------------
__global__ __launch_bounds__(256) void stage2_k(
    const float2* __restrict__ Up, const float* __restrict__ arr,
    const float* __restrict__ aii, float* __restrict__ yf)
{
  __shared__ float2 Us[128 * 16];
  __shared__ float ars[128], ais[128];
  int jg = blockIdx.x, i = blockIdx.y;
  int t = threadIdx.x;
  const float2* UpI = Up + i * NPIX;
  for (int p = t; p < 2048; p += 256) {
    int y = p >> 4, jj = p & 15;
    Us[p] = UpI[y * 128 + jg * 16 + jj];
  }
  if (t < 128) { ars[t] = arr[t]; ais[t] = aii[t]; }
  __syncthreads();
  int yp = t & 127;
  int xsl = t >> 7;
  float acc[8];
#pragma unroll
  for (int xx = 0; xx < 8; ++xx) acc[xx] = 0.f;
  for (int y = 0; y < 128; ++y) {
    float tr = ars[(yp - y) & 127];
    float ti = ais[(yp - y) & 127];
#pragma unroll
    for (int xx = 0; xx < 8; ++xx) {
      float2 u = Us[y * 16 + xsl * 8 + xx];
      acc[xx] += u.x * tr - u.y * ti;
    }
  }
  float* yfI = yf + i * NPIX;
  int xb = jg * 16 + xsl * 8;
#pragma unroll
  for (int xx = 0; xx < 8; ++xx)
    yfI[yp * 128 + xb + xx] = acc[xx];
}

// ---------------------------------------------------------------------------
// K4a: inner 3x3 circular conv as MFMA GEMM per i (unchanged from R13, passing)
// ---------------------------------------------------------------------------
__global__ __launch_bounds__(256, 3) void stageA_k(
    const float* __restrict__ yf, const unsigned short* __restrict__ wsplit,
    unsigned short* __restrict__ xfg)
{
  __shared__ unsigned int bpU[512];
  __shared__ __align__(16) unsigned int BU[256 * 34];
  int Y0 = blockIdx.x * 2, i = blockIdx.y;
  int tid = threadIdx.x;
  const float* yfi = yf + i * NPIX;

  for (int j = tid; j < 512; j += 256) {
    int r = j >> 7, cx = j & 127;
    int gy = (Y0 - 2 + r) & 127;
    float v = yfi[gy * 128 + cx];
    unsigned short b0 = f2bf(v);
    unsigned short b1 = f2bf(v - bf2f(b0));
    bpU[j] = (unsigned)b0 | ((unsigned)b1 << 16);
  }
  __syncthreads();

  {
    int px = tid;
    int ry = px >> 7, xx = px & 127;
    unsigned int* brow = BU + px * 34;
#pragma unroll
    for (int k = 0; k < 9; ++k) {
      int dy = k / 3, dx = k - dy * 3;
      int r = 2 + ry - dy;
      int c = (xx - dx) & 127;
      unsigned int pr = bpU[r * 128 + c];
      brow[2 * k] = pr;
      brow[2 * k + 1] = pr;
    }
#pragma unroll
    for (int q = 18; q < 34; ++q) brow[q] = 0u;
  }
  __syncthreads();

  int wv = tid >> 6, lane = tid & 63;
  int tx = lane & 15, gq = lane >> 4;
  f32x4 acc[4][3];
#pragma unroll
  for (int nn = 0; nn < 4; ++nn)
#pragma unroll
    for (int m = 0; m < 3; ++m) acc[nn][m] = (f32x4){0.f, 0.f, 0.f, 0.f};

  const unsigned short* wsA = wsplit + i * (48 * 64);
#pragma unroll
  for (int half = 0; half < 2; ++half) {
    bf16x8 Af[3];
#pragma unroll
    for (int m = 0; m < 3; ++m)
      Af[m] = *(const bf16x8*)(wsA + (m * 16 + tx) * 64 + half * 32 + gq * 8);
#pragma unroll
    for (int nn = 0; nn < 4; ++nn) {
      int px = (wv * 4 + nn) * 16 + tx;
      bf16x8 Bf = *(const bf16x8*)((const short*)BU + px * 68 + half * 32 + gq * 8);
#pragma unroll
      for (int m = 0; m < 3; ++m)
        acc[nn][m] = __builtin_amdgcn_mfma_f32_16x16x32_bf16(Af[m], Bf, acc[nn][m], 0, 0, 0);
    }
  }

#pragma unroll
  for (int nn = 0; nn < 4; ++nn) {
    int p = Y0 * 128 + (wv * 4 + nn) * 16 + tx;
#pragma unroll
    for (int m = 0; m < 3; ++m) {
#pragma unroll
      for (int r = 0; r < 4; ++r) {
        int o = m * 16 + gq * 4 + r;
        xfg[((size_t)(o * 48 + i) << 14) + p] = f2bf(acc[nn][m][r]);
      }
    }
  }
}

// ---------------------------------------------------------------------------
// K4b: conv2 gather+GEMM, 32-px-wide tiles.
//  R13's 16-px tiles read 36B (i,row) segments -> 228MB fetch @1.45TB/s =
//  162us, pure fetch-bound. 32-px core read = ONE 64B-aligned line per
//  (i,row) -> ~2x less fetch, line-aligned. LDS XF[612][52]+16 = 63.7KB ->
//  2 blocks/CU at (256,2); acc 2x4x3 f32x4 = 96 AGPR + ~80 arch < 256 cap.
//  NaN invariant: pad [48,52) + tail zeroed; B1 spill -> next row x A=0.
// ---------------------------------------------------------------------------
__global__ __launch_bounds__(256, 2) void conv2g_k(
    const unsigned short* __restrict__ xfg,
    const unsigned short* __restrict__ wbf64, float* __restrict__ out)
{
  __shared__ __align__(16) short XF[612 * XFP + 16];  // 18 rows x 34 cols

  int o  = blockIdx.z;
  int y0 = blockIdx.y * 16, x0 = blockIdx.x * 32;
  int tid = threadIdx.x;

  // phase 0: zero per-row pad shorts [48,52) and tail (NaN invariant)
  for (int p = tid; p < 612; p += 256)
    *(uint2*)(XF + p * XFP + 48) = make_uint2(0u, 0u);
  if (tid < 16) XF[612 * XFP + tid] = 0;

  // phase 1: gather XF[rr*34+cidx][i] from xfg[o][i][p]; zero outside image
  for (int task = tid; task < 864; task += 256) {
    int i = task % 48, rr = task / 48;
    int y = y0 - 1 + rr;
    short* dst = XF + rr * 34 * XFP + i;
    if (y >= 0 && y < 128) {
      const unsigned short* src = xfg + ((size_t)(o * 48 + i) << 14) + (y << 7);
      uint4 q0 = *(const uint4*)(src + x0);        // 64B-aligned full line
      uint4 q1 = *(const uint4*)(src + x0 + 8);
      uint4 q2 = *(const uint4*)(src + x0 + 16);
      uint4 q3 = *(const uint4*)(src + x0 + 24);
      unsigned short e0  = (x0 > 0)        ? src[x0 - 1]  : (unsigned short)0;
      unsigned short e33 = (x0 + 32 < 128) ? src[x0 + 32] : (unsigned short)0;
      unsigned int qs[16] = {q0.x, q0.y, q0.z, q0.w, q1.x, q1.y, q1.z, q1.w,
                             q2.x, q2.y, q2.z, q2.w, q3.x, q3.y, q3.z, q3.w};
      dst[0] = (short)e0;
#pragma unroll
      for (int h = 0; h < 16; ++h) {
        dst[(2 * h + 1) * XFP] = (short)(qs[h] & 0xffffu);
        dst[(2 * h + 2) * XFP] = (short)(qs[h] >> 16);
      }
      dst[33 * XFP] = (short)e33;
    } else {
#pragma unroll
      for (int c = 0; c < 34; ++c) dst[c * XFP] = 0;
    }
  }
  __syncthreads();

  // phase 2: MFMA GEMM over two 16-px halves
  int wv = tid >> 6, lane = tid & 63;
  int tx = lane & 15, gq = lane >> 4;
  f32x4 acc[2][4][3];
#pragma unroll
  for (int h = 0; h < 2; ++h)
#pragma unroll
    for (int nn = 0; nn < 4; ++nn)
#pragma unroll
      for (int m = 0; m < 3; ++m) acc[h][nn][m] = (f32x4){0.f, 0.f, 0.f, 0.f};

  const unsigned short* abase = wbf64 + (tx)*64;

  for (int k = 0; k < 9; ++k) {
    bf16x8 Ac0[3], Ac1[3];
#pragma unroll
    for (int m = 0; m < 3; ++m) {
      const unsigned short* ap = abase + (k * 48 + m * 16) * 64;
      Ac0[m] = *(const bf16x8*)(ap + gq * 8);
      Ac1[m] = *(const bf16x8*)(ap + 32 + gq * 8);
    }
    int dy = k / 3, dx = k - dy * 3;
#pragma unroll
    for (int h = 0; h < 2; ++h) {
#pragma unroll
      for (int nn = 0; nn < 4; ++nn) {
        int n = wv * 4 + nn;
        const short* bp = XF + ((n + dy) * 34 + h * 16 + tx + dx) * XFP;
        bf16x8 B0 = *(const bf16x8*)(bp + gq * 8);
        bf16x8 B1 = *(const bf16x8*)(bp + 32 + gq * 8);  // pad/next-row, A=0
#pragma unroll
        for (int m = 0; m < 3; ++m) {
          acc[h][nn][m] = __builtin_amdgcn_mfma_f32_16x16x32_bf16(Ac0[m], B0, acc[h][nn][m], 0, 0, 0);
          acc[h][nn][m] = __builtin_amdgcn_mfma_f32_16x16x32_bf16(Ac1[m], B1, acc[h][nn][m], 0, 0, 0);
        }
      }
    }
  }

  // epilogue: C frag col=lane&15 (pixel x within half), row=gq*4+r (oc)
#pragma unroll
  for (int h = 0; h < 2; ++h) {
#pragma unroll
    for (int nn = 0; nn < 4; ++nn) {
      int y = y0 + wv * 4 + nn;
#pragma unroll
      for (int m = 0; m < 3; ++m) {
#pragma unroll
        for (int r = 0; r < 4; ++r) {
          int oc = m * 16 + gq * 4 + r;
          out[((size_t)(o * COUT + oc) << 14) + (y << 7) + x0 + h * 16 + tx] = acc[h][nn][m][r];
        }
      }
    }
  }
}

// ---------------------------------------------------------------------------
// K4 (fallback, R12 verbatim): fused stencil + MFMA GEMM, (256,3) no-spill.
// ---------------------------------------------------------------------------
__global__ __launch_bounds__(256, 3) void conv2_k(
    const float* __restrict__ yf, const float* __restrict__ wts,
    const unsigned short* __restrict__ wbf64, float* __restrict__ out)
{
  __shared__ __align__(16) short XF[324 * XFP + 16];

  int o  = blockIdx.z;
  int y0 = blockIdx.y * 16, x0 = blockIdx.x * 16;
  int tid = threadIdx.x;

  for (int p = tid; p < 324; p += 256)
    *(uint2*)(XF + p * XFP + 48) = make_uint2(0u, 0u);
  if (tid < 16) XF[324 * XFP + tid] = 0;

  if (tid < 240) {
    int sA = tid, sB = tid + 240;
    int iA = sA / 10, rA = sA - iA * 10, spA = rA % 5, hA = rA / 5;
    int iB = sB / 10, rB = sB - iB * 10, spB = rB % 5, hB = rB / 5;
    const float* WpA = wts + (o * CIN + iA) * 9;
    const float* WpB = wts + (o * CIN + iB) * 9;
    float WA0 = WpA[0], WA1 = WpA[1], WA2 = WpA[2], WA3 = WpA[3], WA4 = WpA[4],
          WA5 = WpA[5], WA6 = WpA[6], WA7 = WpA[7], WA8 = WpA[8];
    float WB0 = WpB[0], WB1 = WpB[1], WB2 = WpB[2], WB3 = WpB[3], WB4 = WpB[4],
          WB5 = WpB[5], WB6 = WpB[6], WB7 = WpB[7], WB8 = WpB[8];
    const float* yfA = yf + iA * NPIX;
    const float* yfB = yf + iB * NPIX;
    int cbA = (x0 - 4 + 4 * spA) & 127;
    int cbB = (x0 - 4 + 4 * spB) & 127;
    int rbA = hA * 9, rbB = hB * 9;
    float RaA[8], RbA[8], RcA[8], RaB[8], RbB[8], RcB[8];

#define LOADA(dst, ry) { \
    const float* rp_ = yfA + (((ry) & 127) << 7); \
    float4 q0_ = *(const float4*)(rp_ + cbA); \
    float4 q1_ = *(const float4*)(rp_ + ((cbA + 4) & 127)); \
    dst[0]=q0_.x; dst[1]=q0_.y; dst[2]=q0_.z; dst[3]=q0_.w; \
    dst[4]=q1_.x; dst[5]=q1_.y; dst[6]=q1_.z; dst[7]=q1_.w; }
#define LOADB(dst, ry) { \
    const float* rp_ = yfB + (((ry) & 127) << 7); \
    float4 q0_ = *(const float4*)(rp_ + cbB); \
    float4 q1_ = *(const float4*)(rp_ + ((cbB + 4) & 127)); \
    dst[0]=q0_.x; dst[1]=q0_.y; dst[2]=q0_.z; dst[3]=q0_.w; \
    dst[4]=q1_.x; dst[5]=q1_.y; dst[6]=q1_.z; dst[7]=q1_.w; }
#define EMITA(rr, R2_, R1_, R0_) { \
    int y_ = y0 - 1 + (rr); \
    bool yok_ = (y_ >= 0) && (y_ < 128); \
    _Pragma("unroll") \
    for (int j = 0; j < 4; ++j) { \
      int cidx_ = 4 * spA + j; \
      if (cidx_ < 18) { \
        int xg_ = x0 - 1 + cidx_; \
        float v_ = 0.f; \
        if (yok_ && xg_ >= 0 && xg_ < 128) { \
          v_ = WA0 * R0_[j + 3] + WA1 * R0_[j + 2] + WA2 * R0_[j + 1] \
             + WA3 * R1_[j + 3] + WA4 * R1_[j + 2] + WA5 * R1_[j + 1] \
             + WA6 * R2_[j + 3] + WA7 * R2_[j + 2] + WA8 * R2_[j + 1]; \
        } \
        XF[((rr) * 18 + cidx_) * XFP + iA] = (short)f2bf(v_); \
      } } }
#define EMITB(rr, R2_, R1_, R0_) { \
    int y_ = y0 - 1 + (rr); \
    bool yok_ = (y_ >= 0) && (y_ < 128); \
    _Pragma("unroll") \
    for (int j = 0; j < 4; ++j) { \
      int cidx_ = 4 * spB + j; \
      if (cidx_ < 18) { \
        int xg_ = x0 - 1 + cidx_; \
        float v_ = 0.f; \
        if (yok_ && xg_ >= 0 && xg_ < 128) { \
          v_ = WB0 * R0_[j + 3] + WB1 * R0_[j + 2] + WB2 * R0_[j + 1] \
             + WB3 * R1_[j + 3] + WB4 * R1_[j + 2] + WB5 * R1_[j + 1] \
             + WB6 * R2_[j + 3] + WB7 * R2_[j + 2] + WB8 * R2_[j + 1]; \
        } \
        XF[((rr) * 18 + cidx_) * XFP + iB] = (short)f2bf(v_); \
      } } }

    LOADA(RaA, y0 - 3 + rbA)  LOADB(RaB, y0 - 3 + rbB)
    LOADA(RbA, y0 - 2 + rbA)  LOADB(RbB, y0 - 2 + rbB)
#pragma unroll
    for (int rr0 = 0; rr0 < 9; rr0 += 3) {
      LOADA(RcA, y0 - 1 + rbA + rr0)  LOADB(RcB, y0 - 1 + rbB + rr0)
      EMITA(rbA + rr0,     RaA, RbA, RcA)  EMITB(rbB + rr0,     RaB, RbB, RcB)
      LOADA(RaA, y0 + rbA + rr0)      LOADB(RaB, y0 + rbB + rr0)
      EMITA(rbA + rr0 + 1, RbA, RcA, RaA)  EMITB(rbB + rr0 + 1, RbB, RcB, RaB)
      LOADA(RbA, y0 + 1 + rbA + rr0)  LOADB(RbB, y0 + 1 + rbB + rr0)
      EMITA(rbA + rr0 + 2, RcA, RaA, RbA)  EMITB(rbB + rr0 + 2, RcB, RaB, RbB)
    }
#undef LOADA
#undef LOADB
#undef EMITA
#undef EMITB
  }
  __syncthreads();

  int wv = tid >> 6, lane = tid & 63;
  int tx = lane & 15, gq = lane >> 4;
  f32x4 acc[4][3];
#pragma unroll
  for (int nn = 0; nn < 4; ++nn)
#pragma unroll
    for (int m = 0; m < 3; ++m) acc[nn][m] = (f32x4){0.f, 0.f, 0.f, 0.f};

  const unsigned short* abase = wbf64 + (tx)*64;

  for (int k = 0; k < 9; ++k) {
    bf16x8 Ac0[3], Ac1[3];
#pragma unroll
    for (int m = 0; m < 3; ++m) {
      const unsigned short* ap = abase + (k * 48 + m * 16) * 64;
      Ac0[m] = *(const bf16x8*)(ap + gq * 8);
      Ac1[m] = *(const bf16x8*)(ap + 32 + gq * 8);
    }
    int dy = k / 3, dx = k - dy * 3;
#pragma unroll
    for (int nn = 0; nn < 4; ++nn) {
      int n = wv * 4 + nn;
      const short* bp = XF + ((n + dy) * 18 + tx + dx) * XFP;
      bf16x8 B0 = *(const bf16x8*)(bp + gq * 8);
      bf16x8 B1 = *(const bf16x8*)(bp + 32 + gq * 8);
#pragma unroll
      for (int m = 0; m < 3; ++m) {
        acc[nn][m] = __builtin_amdgcn_mfma_f32_16x16x32_bf16(Ac0[m], B0, acc[nn][m], 0, 0, 0);
        acc[nn][m] = __builtin_amdgcn_mfma_f32_16x16x32_bf16(Ac1[m], B1, acc[nn][m], 0, 0, 0);
      }
    }
  }

#pragma unroll
  for (int nn = 0; nn < 4; ++nn) {
    int y = y0 + wv * 4 + nn;
#pragma unroll
    for (int m = 0; m < 3; ++m) {
#pragma unroll
      for (int r = 0; r < 4; ++r) {
        int oc = m * 16 + gq * 4 + r;
        out[((size_t)(o * COUT + oc) << 14) + (y << 7) + x0 + tx] = acc[nn][m][r];
      }
    }
  }
}

// ---------------------------------------------------------------------------
extern "C" void kernel_launch(void* const* d_in, const int* in_sizes, int n_in,
                              void* d_out, int out_size, void* d_ws, size_t ws_size,
                              hipStream_t stream)
{
  const float* x      = (const float*)d_in[0];
  const float* freq   = (const float*)d_in[1];
  const float* theta  = (const float*)d_in[2];
  const float* sigma  = (const float*)d_in[3];
  const float* psi    = (const float*)d_in[4];
  const float* f0     = (const float*)d_in[5];
  const float* theta0 = (const float*)d_in[6];
  float* out = (float*)d_out;
  float* ws  = (float*)d_ws;

  float*  w      = ws;
  float*  ar     = ws + 20736;
  float*  ai     = ws + 20864;
  float2* Up     = (float2*)(ws + OFF_UP);
  float*  yf     = ws + OFF_YF;
  unsigned short* wbf64  = (unsigned short*)(ws + OFF_WBF64);
  unsigned int*   wsplit = (unsigned int*)(ws + OFF_WSPLIT);
  unsigned short* xfg    = (unsigned short*)(ws + OFF_XFG);

  int big = (ws_size >= WS_NEEDED) ? 1 : 0;

  gabor_k<<<dim3(126), dim3(256), 0, stream>>>(freq, theta, sigma, psi, f0, theta0,
                                               w, wbf64, wsplit, big);
  circ_k<<<dim3(1), dim3(128), 0, stream>>>(ar, ai);
  stage1_k<<<dim3(8, 48), dim3(256), 0, stream>>>(x, ar, ai, Up);
  stage2_k<<<dim3(8, 48), dim3(256), 0, stream>>>(Up, ar, ai, yf);
  if (big) {
    stageA_k<<<dim3(64, 48), dim3(256), 0, stream>>>(yf, (const unsigned short*)wsplit, xfg);
    conv2g_k<<<dim3(4, 8, 48), dim3(256), 0, stream>>>(xfg, wbf64, out);
  } else {
    conv2_k<<<dim3(8, 8, 48), dim3(256), 0, stream>>>(yf, w, wbf64, out);
  }
}

// Round 15
// 192.812 us; speedup vs baseline: 1.1953x; 1.0656x over previous
//
#include <hip/hip_runtime.h>

#define CIN 48
#define COUT 48
#define NPIX 16384  // 128*128
#define XFP 52      // XF pitch in shorts (104 B): bank conflicts 5.8M -> 0.88M (R11/R12)

typedef float f32x4 __attribute__((ext_vector_type(4)));
typedef short bf16x8 __attribute__((ext_vector_type(8)));

__device__ __forceinline__ unsigned short f2bf(float f) {
  unsigned u = __float_as_uint(f);
  unsigned r = (u + 0x7FFFu + ((u >> 16) & 1u)) >> 16;  // RNE
  return (unsigned short)r;
}
__device__ __forceinline__ float bf2f(unsigned short b) {
  return __uint_as_float(((unsigned)b) << 16);
}

// ws layout (floats):
//   w[20736] | ar[128] | ai[128] | pad->21248 | Up[1572864] | yf[786432] |
//   wbf64[13824] | wsplit[73728] | xfg[18874368]
#define OFF_UP     21248
#define OFF_YF     (OFF_UP + CIN * NPIX * 2)
#define OFF_WBF64  (OFF_YF + CIN * NPIX)
#define OFF_WSPLIT (OFF_WBF64 + 13824)
#define OFF_XFG    (OFF_WSPLIT + 73728)
#define WS_NEEDED  ((size_t)(OFF_XFG + 48 * 48 * NPIX / 2) * 4)

// ---------------------------------------------------------------------------
// K1: Gabor weights (unchanged, passing)
// ---------------------------------------------------------------------------
__global__ __launch_bounds__(256) void gabor_k(
    const float* __restrict__ freq, const float* __restrict__ theta,
    const float* __restrict__ sigma, const float* __restrict__ psi,
    const float* __restrict__ f0, const float* __restrict__ theta0,
    float* __restrict__ wout, unsigned short* __restrict__ wbf64,
    unsigned int* __restrict__ wsplitU, int big)
{
  int idx = blockIdx.x * 256 + threadIdx.x;
  if (idx < 432 * 16) {
    wbf64[(idx >> 4) * 64 + 48 + (idx & 15)] = 0;
  }
  if (big && idx < 2304 * 14) {
    int row = idx / 14, q = idx - row * 14;
    wsplitU[row * 32 + 18 + q] = 0u;
  }
  if (idx >= COUT * CIN * 9) return;
  int k = idx % 9;
  int oi = idx / 9;
  int oc = oi / CIN, ic = oi % CIN;
  int a = k / 3, b = k % 3;
  float Yv = (a == 0) ? -1.0f : ((a == 1) ? 0.5f : 2.0f);
  float Xv = (b == 0) ? -1.0f : ((b == 1) ? 0.5f : 2.0f);
  float th = theta[oi], sg = sigma[oi], fr = freq[oi], ps = psi[oi];
  float F0 = f0[oi], th0 = theta0[oi];
  float c = cosf(th), s = sinf(th);
  float rotx =  Xv * c + Yv * s;
  float roty = -Xv * s + Yv * c;
  float r = sqrtf(rotx * rotx + roty * roty + 0.001f);
  float denom = 2.0f * logf(sg / F0);
  float t1 = (logf(r) - logf(F0)) / denom;
  float g_rad = expf(-t1 * t1);
  float dth = th - th0;
  float g_ang = expf(-dth * dth / (2.0f * sg * sg));
  float g = g_rad * g_ang * cosf(fr * r + ps) / (6.283185307179586f * sg * sg);
  wout[idx] = g;
  wbf64[(k * 48 + oc) * 64 + ic] = f2bf(g);
  if (big) {
    unsigned short w0 = f2bf(g);
    unsigned short w1 = f2bf(g - bf2f(w0));
    unsigned int u0 = (unsigned)w0 | ((unsigned)w0 << 16);
    unsigned int u1 = (unsigned)w1 | ((unsigned)w1 << 16);
    unsigned int* rowp = wsplitU + (ic * 48 + oc) * 32;
    rowp[k * 2]     = u0;
    rowp[k * 2 + 1] = u1;
  }
}

// ---------------------------------------------------------------------------
// K2: circulant band-limit vector
// ---------------------------------------------------------------------------
__global__ void circ_k(float* __restrict__ ar, float* __restrict__ ai)
{
  int d = threadIdx.x;
  float sr = 0.f, si = 0.f;
  for (int u = 34; u < 94; ++u) {
    int m = (u * d) & 127;
    float ang = (float)m * 0.049087385212340526f;
    sr += cosf(ang);
    si += sinf(ang);
  }
  ar[d] = sr * (1.0f / 128.0f);
  ai[d] = si * (1.0f / 128.0f);
}

// ---------------------------------------------------------------------------
// K3a: row band-limit. grid (8, 48).
// ---------------------------------------------------------------------------
__global__ __launch_bounds__(256) void stage1_k(
    const float* __restrict__ x, const float* __restrict__ arr,
    const float* __restrict__ aii, float2* __restrict__ Up)
{
  __shared__ float Xs[16 * 128];
  __shared__ float ars[128], ais[128];
  int yg = blockIdx.x, i = blockIdx.y;
  int t = threadIdx.x;
  const float* Xi = x + i * NPIX + yg * 16 * 128;
  for (int p = t; p < 2048; p += 256) Xs[p] = Xi[p];
  if (t < 128) { ars[t] = arr[t]; ais[t] = aii[t]; }
  __syncthreads();
  int j = t & 127;
  int ysl = t >> 7;
  float accr[8], acci[8];
#pragma unroll
  for (int yy = 0; yy < 8; ++yy) { accr[yy] = 0.f; acci[yy] = 0.f; }
  for (int xx = 0; xx < 128; ++xx) {
    float tr = ars[(j - xx) & 127];
    float ti = ais[(j - xx) & 127];
#pragma unroll
    for (int yy = 0; yy < 8; ++yy) {
      float xv = Xs[(ysl * 8 + yy) * 128 + xx];
      accr[yy] += xv * tr;
      acci[yy] += xv * ti;
    }
  }
  float2* UpI = Up + i * NPIX;
  int ybase = yg * 16 + ysl * 8;
#pragma unroll
  for (int yy = 0; yy < 8; ++yy)
    UpI[(ybase + yy) * 128 + j] = make_float2(accr[yy], acci[yy]);
}

// ---------------------------------------------------------------------------
// K3b: column band-limit. grid (8, 48). f32 output (R7: bf16 yf fails).
// ---------------------------------------------------------------------------
__global__ __launch_bounds__(256) void stage2_k(
    const float2* __restrict__ Up, const float* __restrict__ arr,
    const float* __restrict__ aii, float* __restrict__ yf)
{
  __shared__ float2 Us[128 * 16];
  __shared__ float ars[128], ais[128];
  int jg = blockIdx.x, i = blockIdx.y;
  int t = threadIdx.x;
  const float2* UpI = Up + i * NPIX;
  for (int p = t; p < 2048; p += 256) {
    int y = p >> 4, jj = p & 15;
    Us[p] = UpI[y * 128 + jg * 16 + jj];
  }
  if (t < 128) { ars[t] = arr[t]; ais[t] = aii[t]; }
  __syncthreads();
  int yp = t & 127;
  int xsl = t >> 7;
  float acc[8];
#pragma unroll
  for (int xx = 0; xx < 8; ++xx) acc[xx] = 0.f;
  for (int y = 0; y < 128; ++y) {
    float tr = ars[(yp - y) & 127];
    float ti = ais[(yp - y) & 127];
#pragma unroll
    for (int xx = 0; xx < 8; ++xx) {
      float2 u = Us[y * 16 + xsl * 8 + xx];
      acc[xx] += u.x * tr - u.y * ti;
    }
  }
  float* yfI = yf + i * NPIX;
  int xb = jg * 16 + xsl * 8;
#pragma unroll
  for (int xx = 0; xx < 8; ++xx)
    yfI[yp * 128 + xb + xx] = acc[xx];
}

// ---------------------------------------------------------------------------
// K4a: inner 3x3 circular conv as MFMA GEMM per i (unchanged, passing)
// ---------------------------------------------------------------------------
__global__ __launch_bounds__(256, 3) void stageA_k(
    const float* __restrict__ yf, const unsigned short* __restrict__ wsplit,
    unsigned short* __restrict__ xfg)
{
  __shared__ unsigned int bpU[512];
  __shared__ __align__(16) unsigned int BU[256 * 34];
  int Y0 = blockIdx.x * 2, i = blockIdx.y;
  int tid = threadIdx.x;
  const float* yfi = yf + i * NPIX;

  for (int j = tid; j < 512; j += 256) {
    int r = j >> 7, cx = j & 127;
    int gy = (Y0 - 2 + r) & 127;
    float v = yfi[gy * 128 + cx];
    unsigned short b0 = f2bf(v);
    unsigned short b1 = f2bf(v - bf2f(b0));
    bpU[j] = (unsigned)b0 | ((unsigned)b1 << 16);
  }
  __syncthreads();

  {
    int px = tid;
    int ry = px >> 7, xx = px & 127;
    unsigned int* brow = BU + px * 34;
#pragma unroll
    for (int k = 0; k < 9; ++k) {
      int dy = k / 3, dx = k - dy * 3;
      int r = 2 + ry - dy;
      int c = (xx - dx) & 127;
      unsigned int pr = bpU[r * 128 + c];
      brow[2 * k] = pr;
      brow[2 * k + 1] = pr;
    }
#pragma unroll
    for (int q = 18; q < 34; ++q) brow[q] = 0u;
  }
  __syncthreads();

  int wv = tid >> 6, lane = tid & 63;
  int tx = lane & 15, gq = lane >> 4;
  f32x4 acc[4][3];
#pragma unroll
  for (int nn = 0; nn < 4; ++nn)
#pragma unroll
    for (int m = 0; m < 3; ++m) acc[nn][m] = (f32x4){0.f, 0.f, 0.f, 0.f};

  const unsigned short* wsA = wsplit + i * (48 * 64);
#pragma unroll
  for (int half = 0; half < 2; ++half) {
    bf16x8 Af[3];
#pragma unroll
    for (int m = 0; m < 3; ++m)
      Af[m] = *(const bf16x8*)(wsA + (m * 16 + tx) * 64 + half * 32 + gq * 8);
#pragma unroll
    for (int nn = 0; nn < 4; ++nn) {
      int px = (wv * 4 + nn) * 16 + tx;
      bf16x8 Bf = *(const bf16x8*)((const short*)BU + px * 68 + half * 32 + gq * 8);
#pragma unroll
      for (int m = 0; m < 3; ++m)
        acc[nn][m] = __builtin_amdgcn_mfma_f32_16x16x32_bf16(Af[m], Bf, acc[nn][m], 0, 0, 0);
    }
  }

#pragma unroll
  for (int nn = 0; nn < 4; ++nn) {
    int p = Y0 * 128 + (wv * 4 + nn) * 16 + tx;
#pragma unroll
    for (int m = 0; m < 3; ++m) {
#pragma unroll
      for (int r = 0; r < 4; ++r) {
        int o = m * 16 + gq * 4 + r;
        xfg[((size_t)(o * 48 + i) << 14) + p] = f2bf(acc[nn][m][r]);
      }
    }
  }
}

// ---------------------------------------------------------------------------
// K4b: conv2 gather+GEMM, 8-row x 32-col tiles.
//  R14's 16-row tile had 64KB LDS -> 2 blocks/CU, 19% occupancy, 2.1TB/s
//  effective (latency-bound, NOT BW-bound). 8-row tile: LDS = 340x52x2 =
//  35.4KB -> 4 blocks by LDS, (256,3) no-spill bound -> 12 waves/CU (37.5%).
//  Cost: y-halo overlap 10/8 vs 18/16 -> fetch +11%.
//  acc 2 rows/wave x 2 halves x 3 m = 48 AGPR (R12's proven budget).
//  NaN invariant: pad [48,52) + 16-short tail zeroed; B1 spill (gq=3,
//  shorts 56..63) lands in next row's i<16 x A=0, or row 339 -> tail.
// ---------------------------------------------------------------------------
__global__ __launch_bounds__(256, 3) void conv2g_k(
    const unsigned short* __restrict__ xfg,
    const unsigned short* __restrict__ wbf64, float* __restrict__ out)
{
  __shared__ __align__(16) short XF[340 * XFP + 16];  // 10 rows x 34 cols

  int o  = blockIdx.z;
  int y0 = blockIdx.y * 8, x0 = blockIdx.x * 32;
  int tid = threadIdx.x;

  // phase 0: zero per-row pad shorts [48,52) and tail (NaN invariant)
  for (int p = tid; p < 340; p += 256)
    *(uint2*)(XF + p * XFP + 48) = make_uint2(0u, 0u);
  if (tid < 16) XF[340 * XFP + tid] = 0;

  // phase 1: gather XF[rr*34+cidx][i] from xfg[o][i][p]; zero outside image
  for (int task = tid; task < 480; task += 256) {
    int i = task % 48, rr = task / 48;
    int y = y0 - 1 + rr;
    short* dst = XF + rr * 34 * XFP + i;
    if (y >= 0 && y < 128) {
      const unsigned short* src = xfg + ((size_t)(o * 48 + i) << 14) + (y << 7);
      uint4 q0 = *(const uint4*)(src + x0);        // 64B-aligned full line
      uint4 q1 = *(const uint4*)(src + x0 + 8);
      uint4 q2 = *(const uint4*)(src + x0 + 16);
      uint4 q3 = *(const uint4*)(src + x0 + 24);
      unsigned short e0  = (x0 > 0)        ? src[x0 - 1]  : (unsigned short)0;
      unsigned short e33 = (x0 + 32 < 128) ? src[x0 + 32] : (unsigned short)0;
      unsigned int qs[16] = {q0.x, q0.y, q0.z, q0.w, q1.x, q1.y, q1.z, q1.w,
                             q2.x, q2.y, q2.z, q2.w, q3.x, q3.y, q3.z, q3.w};
      dst[0] = (short)e0;
#pragma unroll
      for (int h = 0; h < 16; ++h) {
        dst[(2 * h + 1) * XFP] = (short)(qs[h] & 0xffffu);
        dst[(2 * h + 2) * XFP] = (short)(qs[h] >> 16);
      }
      dst[33 * XFP] = (short)e33;
    } else {
#pragma unroll
      for (int c = 0; c < 34; ++c) dst[c * XFP] = 0;
    }
  }
  __syncthreads();

  // phase 2: MFMA GEMM over two 16-px halves, 2 y-rows per wave
  int wv = tid >> 6, lane = tid & 63;
  int tx = lane & 15, gq = lane >> 4;
  f32x4 acc[2][2][3];
#pragma unroll
  for (int h = 0; h < 2; ++h)
#pragma unroll
    for (int nn = 0; nn < 2; ++nn)
#pragma unroll
      for (int m = 0; m < 3; ++m) acc[h][nn][m] = (f32x4){0.f, 0.f, 0.f, 0.f};

  const unsigned short* abase = wbf64 + (tx)*64;

  for (int k = 0; k < 9; ++k) {
    bf16x8 Ac0[3], Ac1[3];
#pragma unroll
    for (int m = 0; m < 3; ++m) {
      const unsigned short* ap = abase + (k * 48 + m * 16) * 64;
      Ac0[m] = *(const bf16x8*)(ap + gq * 8);
      Ac1[m] = *(const bf16x8*)(ap + 32 + gq * 8);
    }
    int dy = k / 3, dx = k - dy * 3;
#pragma unroll
    for (int h = 0; h < 2; ++h) {
#pragma unroll
      for (int nn = 0; nn < 2; ++nn) {
        int n = wv * 2 + nn;
        const short* bp = XF + ((n + dy) * 34 + h * 16 + tx + dx) * XFP;
        bf16x8 B0 = *(const bf16x8*)(bp + gq * 8);
        bf16x8 B1 = *(const bf16x8*)(bp + 32 + gq * 8);  // pad/next-row, A=0
#pragma unroll
        for (int m = 0; m < 3; ++m) {
          acc[h][nn][m] = __builtin_amdgcn_mfma_f32_16x16x32_bf16(Ac0[m], B0, acc[h][nn][m], 0, 0, 0);
          acc[h][nn][m] = __builtin_amdgcn_mfma_f32_16x16x32_bf16(Ac1[m], B1, acc[h][nn][m], 0, 0, 0);
        }
      }
    }
  }

  // epilogue: C frag col=lane&15 (pixel x within half), row=gq*4+r (oc)
#pragma unroll
  for (int h = 0; h < 2; ++h) {
#pragma unroll
    for (int nn = 0; nn < 2; ++nn) {
      int y = y0 + wv * 2 + nn;
#pragma unroll
      for (int m = 0; m < 3; ++m) {
#pragma unroll
        for (int r = 0; r < 4; ++r) {
          int oc = m * 16 + gq * 4 + r;
          out[((size_t)(o * COUT + oc) << 14) + (y << 7) + x0 + h * 16 + tx] = acc[h][nn][m][r];
        }
      }
    }
  }
}

// ---------------------------------------------------------------------------
// K4 (fallback, R12 verbatim): fused stencil + MFMA GEMM, (256,3) no-spill.
// ---------------------------------------------------------------------------
__global__ __launch_bounds__(256, 3) void conv2_k(
    const float* __restrict__ yf, const float* __restrict__ wts,
    const unsigned short* __restrict__ wbf64, float* __restrict__ out)
{
  __shared__ __align__(16) short XF[324 * XFP + 16];

  int o  = blockIdx.z;
  int y0 = blockIdx.y * 16, x0 = blockIdx.x * 16;
  int tid = threadIdx.x;

  for (int p = tid; p < 324; p += 256)
    *(uint2*)(XF + p * XFP + 48) = make_uint2(0u, 0u);
  if (tid < 16) XF[324 * XFP + tid] = 0;

  if (tid < 240) {
    int sA = tid, sB = tid + 240;
    int iA = sA / 10, rA = sA - iA * 10, spA = rA % 5, hA = rA / 5;
    int iB = sB / 10, rB = sB - iB * 10, spB = rB % 5, hB = rB / 5;
    const float* WpA = wts + (o * CIN + iA) * 9;
    const float* WpB = wts + (o * CIN + iB) * 9;
    float WA0 = WpA[0], WA1 = WpA[1], WA2 = WpA[2], WA3 = WpA[3], WA4 = WpA[4],
          WA5 = WpA[5], WA6 = WpA[6], WA7 = WpA[7], WA8 = WpA[8];
    float WB0 = WpB[0], WB1 = WpB[1], WB2 = WpB[2], WB3 = WpB[3], WB4 = WpB[4],
          WB5 = WpB[5], WB6 = WpB[6], WB7 = WpB[7], WB8 = WpB[8];
    const float* yfA = yf + iA * NPIX;
    const float* yfB = yf + iB * NPIX;
    int cbA = (x0 - 4 + 4 * spA) & 127;
    int cbB = (x0 - 4 + 4 * spB) & 127;
    int rbA = hA * 9, rbB = hB * 9;
    float RaA[8], RbA[8], RcA[8], RaB[8], RbB[8], RcB[8];

#define LOADA(dst, ry) { \
    const float* rp_ = yfA + (((ry) & 127) << 7); \
    float4 q0_ = *(const float4*)(rp_ + cbA); \
    float4 q1_ = *(const float4*)(rp_ + ((cbA + 4) & 127)); \
    dst[0]=q0_.x; dst[1]=q0_.y; dst[2]=q0_.z; dst[3]=q0_.w; \
    dst[4]=q1_.x; dst[5]=q1_.y; dst[6]=q1_.z; dst[7]=q1_.w; }
#define LOADB(dst, ry) { \
    const float* rp_ = yfB + (((ry) & 127) << 7); \
    float4 q0_ = *(const float4*)(rp_ + cbB); \
    float4 q1_ = *(const float4*)(rp_ + ((cbB + 4) & 127)); \
    dst[0]=q0_.x; dst[1]=q0_.y; dst[2]=q0_.z; dst[3]=q0_.w; \
    dst[4]=q1_.x; dst[5]=q1_.y; dst[6]=q1_.z; dst[7]=q1_.w; }
#define EMITA(rr, R2_, R1_, R0_) { \
    int y_ = y0 - 1 + (rr); \
    bool yok_ = (y_ >= 0) && (y_ < 128); \
    _Pragma("unroll") \
    for (int j = 0; j < 4; ++j) { \
      int cidx_ = 4 * spA + j; \
      if (cidx_ < 18) { \
        int xg_ = x0 - 1 + cidx_; \
        float v_ = 0.f; \
        if (yok_ && xg_ >= 0 && xg_ < 128) { \
          v_ = WA0 * R0_[j + 3] + WA1 * R0_[j + 2] + WA2 * R0_[j + 1] \
             + WA3 * R1_[j + 3] + WA4 * R1_[j + 2] + WA5 * R1_[j + 1] \
             + WA6 * R2_[j + 3] + WA7 * R2_[j + 2] + WA8 * R2_[j + 1]; \
        } \
        XF[((rr) * 18 + cidx_) * XFP + iA] = (short)f2bf(v_); \
      } } }
#define EMITB(rr, R2_, R1_, R0_) { \
    int y_ = y0 - 1 + (rr); \
    bool yok_ = (y_ >= 0) && (y_ < 128); \
    _Pragma("unroll") \
    for (int j = 0; j < 4; ++j) { \
      int cidx_ = 4 * spB + j; \
      if (cidx_ < 18) { \
        int xg_ = x0 - 1 + cidx_; \
        float v_ = 0.f; \
        if (yok_ && xg_ >= 0 && xg_ < 128) { \
          v_ = WB0 * R0_[j + 3] + WB1 * R0_[j + 2] + WB2 * R0_[j + 1] \
             + WB3 * R1_[j + 3] + WB4 * R1_[j + 2] + WB5 * R1_[j + 1] \
             + WB6 * R2_[j + 3] + WB7 * R2_[j + 2] + WB8 * R2_[j + 1]; \
        } \
        XF[((rr) * 18 + cidx_) * XFP + iB] = (short)f2bf(v_); \
      } } }

    LOADA(RaA, y0 - 3 + rbA)  LOADB(RaB, y0 - 3 + rbB)
    LOADA(RbA, y0 - 2 + rbA)  LOADB(RbB, y0 - 2 + rbB)
#pragma unroll
    for (int rr0 = 0; rr0 < 9; rr0 += 3) {
      LOADA(RcA, y0 - 1 + rbA + rr0)  LOADB(RcB, y0 - 1 + rbB + rr0)
      EMITA(rbA + rr0,     RaA, RbA, RcA)  EMITB(rbB + rr0,     RaB, RbB, RcB)
      LOADA(RaA, y0 + rbA + rr0)      LOADB(RaB, y0 + rbB + rr0)
      EMITA(rbA + rr0 + 1, RbA, RcA, RaA)  EMITB(rbB + rr0 + 1, RbB, RcB, RaB)
      LOADA(RbA, y0 + 1 + rbA + rr0)  LOADB(RbB, y0 + 1 + rbB + rr0)
      EMITA(rbA + rr0 + 2, RcA, RaA, RbA)  EMITB(rbB + rr0 + 2, RcB, RaB, RbB)
    }
#undef LOADA
#undef LOADB
#undef EMITA
#undef EMITB
  }
  __syncthreads();

  int wv = tid >> 6, lane = tid & 63;
  int tx = lane & 15, gq = lane >> 4;
  f32x4 acc[4][3];
#pragma unroll
  for (int nn = 0; nn < 4; ++nn)
#pragma unroll
    for (int m = 0; m < 3; ++m) acc[nn][m] = (f32x4){0.f, 0.f, 0.f, 0.f};

  const unsigned short* abase = wbf64 + (tx)*64;

  for (int k = 0; k < 9; ++k) {
    bf16x8 Ac0[3], Ac1[3];
#pragma unroll
    for (int m = 0; m < 3; ++m) {
      const unsigned short* ap = abase + (k * 48 + m * 16) * 64;
      Ac0[m] = *(const bf16x8*)(ap + gq * 8);
      Ac1[m] = *(const bf16x8*)(ap + 32 + gq * 8);
    }
    int dy = k / 3, dx = k - dy * 3;
#pragma unroll
    for (int nn = 0; nn < 4; ++nn) {
      int n = wv * 4 + nn;
      const short* bp = XF + ((n + dy) * 18 + tx + dx) * XFP;
      bf16x8 B0 = *(const bf16x8*)(bp + gq * 8);
      bf16x8 B1 = *(const bf16x8*)(bp + 32 + gq * 8);
#pragma unroll
      for (int m = 0; m < 3; ++m) {
        acc[nn][m] = __builtin_amdgcn_mfma_f32_16x16x32_bf16(Ac0[m], B0, acc[nn][m], 0, 0, 0);
        acc[nn][m] = __builtin_amdgcn_mfma_f32_16x16x32_bf16(Ac1[m], B1, acc[nn][m], 0, 0, 0);
      }
    }
  }

#pragma unroll
  for (int nn = 0; nn < 4; ++nn) {
    int y = y0 + wv * 4 + nn;
#pragma unroll
    for (int m = 0; m < 3; ++m) {
#pragma unroll
      for (int r = 0; r < 4; ++r) {
        int oc = m * 16 + gq * 4 + r;
        out[((size_t)(o * COUT + oc) << 14) + (y << 7) + x0 + tx] = acc[nn][m][r];
      }
    }
  }
}

// ---------------------------------------------------------------------------
extern "C" void kernel_launch(void* const* d_in, const int* in_sizes, int n_in,
                              void* d_out, int out_size, void* d_ws, size_t ws_size,
                              hipStream_t stream)
{
  const float* x      = (const float*)d_in[0];
  const float* freq   = (const float*)d_in[1];
  const float* theta  = (const float*)d_in[2];
  const float* sigma  = (const float*)d_in[3];
  const float* psi    = (const float*)d_in[4];
  const float* f0     = (const float*)d_in[5];
  const float* theta0 = (const float*)d_in[6];
  float* out = (float*)d_out;
  float* ws  = (float*)d_ws;

  float*  w      = ws;
  float*  ar     = ws + 20736;
  float*  ai     = ws + 20864;
  float2* Up     = (float2*)(ws + OFF_UP);
  float*  yf     = ws + OFF_YF;
  unsigned short* wbf64  = (unsigned short*)(ws + OFF_WBF64);
  unsigned int*   wsplit = (unsigned int*)(ws + OFF_WSPLIT);
  unsigned short* xfg    = (unsigned short*)(ws + OFF_XFG);

  int big = (ws_size >= WS_NEEDED) ? 1 : 0;

  gabor_k<<<dim3(126), dim3(256), 0, stream>>>(freq, theta, sigma, psi, f0, theta0,
                                               w, wbf64, wsplit, big);
  circ_k<<<dim3(1), dim3(128), 0, stream>>>(ar, ai);
  stage1_k<<<dim3(8, 48), dim3(256), 0, stream>>>(x, ar, ai, Up);
  stage2_k<<<dim3(8, 48), dim3(256), 0, stream>>>(Up, ar, ai, yf);
  if (big) {
    stageA_k<<<dim3(64, 48), dim3(256), 0, stream>>>(yf, (const unsigned short*)wsplit, xfg);
    conv2g_k<<<dim3(4, 16, 48), dim3(256), 0, stream>>>(xfg, wbf64, out);
  } else {
    conv2_k<<<dim3(8, 8, 48), dim3(256), 0, stream>>>(yf, w, wbf64, out);
  }
}